// Round 15
// baseline (300.638 us; speedup 1.0000x reference)
//
#include <hip/hip_runtime.h>
#include <hip/hip_cooperative_groups.h>
#include <math.h>

namespace cg = cooperative_groups;

// Problem constants: B=32, C=256, H=W=56, group=4, d=1
constexpr int B_  = 32;
constexpr int C_  = 256;
constexpr int G_  = 4;
constexpr int K_  = 64;
constexpr int P_  = 3136;        // 56*56
constexpr int NB_ = 29;
constexpr int BG_ = 128;         // B*G
constexpr int CP_ = C_ * P_;
constexpr int N_  = B_ * CP_;
constexpr int N4_ = N_ / 4;
constexpr int HP_ = 29 * 56;     // 1624, half-plane points
constexpr int UA_ = BG_ * 14;    // 1792 phase-A/D units
constexpr int UB_ = BG_ * 8;     // 1024 phase-B/C units
constexpr float TWO_PI = 6.283185307179586f;

typedef float f4_t __attribute__((ext_vector_type(4)));

// Radial bin label in RAW coords, p = a*56+b (symmetric in a,b and mirrors).
__host__ __device__ constexpr int lab_of(int p) {
    int h = p / 56, w = p - h * 56;
    int hh = ((h + 28) % 56) - 28;
    int ww = ((w + 28) % 56) - 28;
    int r2 = hh * hh + ww * ww;
    int rf = 0;
    while ((rf + 1) * (rf + 1) <= r2) ++rf;
    if (rf > 28) rf = 28;
    return rf;
}

struct CntTable { float inv[NB_]; };
constexpr CntTable make_cnt() {
    CntTable t{};
    int c[NB_] = {};
    for (int p = 0; p < P_; ++p) ++c[lab_of(p)];
    for (int i = 0; i < NB_; ++i) t.inv[i] = 1.0f / (float)c[i];
    return t;
}
constexpr CntTable CNT = make_cnt();

__device__ __forceinline__ unsigned fkey(float f) {
    unsigned u = __float_as_uint(f);
    return (u & 0x80000000u) ? ~u : (u | 0x80000000u);
}
__device__ __forceinline__ float fdec(unsigned k) {
    return (k & 0x80000000u) ? __uint_as_float(k ^ 0x80000000u) : __uint_as_float(~k);
}

// ============ Cooperative single-dispatch path (grid-stride phases) ============
__global__ __launch_bounds__(256) void fused_kernel(const float* __restrict__ feature,
                                                    const float* __restrict__ gamma,
                                                    const float* __restrict__ fc_w,
                                                    const float* __restrict__ fc_b,
                                                    float2* __restrict__ tmpF,   // reused as A_s
                                                    float2* __restrict__ specS,
                                                    float* __restrict__ nf,
                                                    float* __restrict__ sums,
                                                    unsigned* __restrict__ mnmx,
                                                    float* __restrict__ out) {
    cg::grid_group grid = cg::this_grid();
    int blk = blockIdx.x, t = threadIdx.x, gdim = gridDim.x;
    __shared__ float2 sA[4 * 57];
    __shared__ float2 sB[4 * 57];
    __shared__ float2 w56[56];
    __shared__ float2 w8[8];
    __shared__ float  misc[512];

    // Forward twiddles.
    if (t < 56) { float a = -TWO_PI * (float)t / 56.f; w56[t] = make_float2(cosf(a), sinf(a)); }
    if (t < 8)  { float a = -TWO_PI * (float)t / 8.f;  w8[t]  = make_float2(cosf(a), sinf(a)); }
    __syncthreads();

    // ---- Phase A: comp (mean+max over K) + row-DFT F1 (Hermitian half) ----
    for (int u = blk; u < UA_; u += gdim) {
        int bg = u / 14, rblk = u - bg * 14, r0 = rblk * 4;
        int b = bg >> 2, g = bg & 3;
        if (rblk == 0) {
            if (t < NB_) sums[bg * NB_ + t] = 0.f;
            else if (t == NB_)     mnmx[bg * 2]     = 0xFFFFFFFFu;
            else if (t == NB_ + 1) mnmx[bg * 2 + 1] = 0u;
        }
        float* sxf = (float*)sA;
        if (t < 224) {
            const float* base = feature + (b * C_ + g * K_) * P_ + r0 * 56 + t;
            float sum = 0.f, mx = -INFINITY;
#pragma unroll 8
            for (int k = 0; k < K_; ++k) {
                float v = base[k * P_];
                sum += v;
                mx = fmaxf(mx, v);
            }
            sxf[(t / 56) * 57 + (t % 56)] = sum * (1.f / 64.f) + mx;
        }
        __syncthreads();
        if (t < 224) {     // stage 1, real input
            int r = t / 56, j = t - r * 56;
            int n1 = j >> 3, k0 = j & 7;
            float sr = 0.f, si = 0.f; int i8 = 0;
            for (int n2 = 0; n2 < 8; ++n2) {
                float v = sxf[r * 57 + 7 * n2 + n1];
                float2 w = w8[i8];
                sr = fmaf(v, w.x, sr);
                si = fmaf(v, w.y, si);
                i8 = (i8 + k0) & 7;
            }
            sB[r * 57 + j] = make_float2(sr, si);
        }
        __syncthreads();
        if (t < 116) {     // stage 2: 29 kw x 4 rows
            int r = t & 3, k = t >> 2;
            float sr = 0.f, si = 0.f; int idx = 0;
            for (int n1 = 0; n1 < 7; ++n1) {
                float2 a = sB[r * 57 + (n1 << 3) + (k & 7)];
                float2 w = w56[idx];
                sr = fmaf(a.x, w.x, fmaf(-a.y, w.y, sr));
                si = fmaf(a.x, w.y, fmaf( a.y, w.x, si));
                idx += k; if (idx >= 56) idx -= 56;
            }
            tmpF[bg * HP_ + k * 56 + (r0 + r)] = make_float2(sr, si);
        }
        __syncthreads();
    }
    grid.sync();

    // ---- Phase B: F2 (col DFT over h) + radial bin sums ----
    for (int u = blk; u < UB_; u += gdim) {
        int bg = u >> 3, kw0 = (u & 7) * 4;
        if (t < NB_) misc[t] = 0.f;
        if (t < 224) {
            int r = t / 56, c = t - r * 56;
            if (kw0 + r <= 28) sA[r * 57 + c] = tmpF[bg * HP_ + (kw0 + r) * 56 + c];
        }
        __syncthreads();
        if (t < 224) {     // stage 1
            int r = t / 56, j = t - r * 56;
            int n1 = j >> 3, k0 = j & 7;
            float sr = 0.f, si = 0.f; int i8 = 0;
            for (int n2 = 0; n2 < 8; ++n2) {
                float2 a = sA[r * 57 + 7 * n2 + n1];
                float2 w = w8[i8];
                sr = fmaf(a.x, w.x, fmaf(-a.y, w.y, sr));
                si = fmaf(a.x, w.y, fmaf( a.y, w.x, si));
                i8 = (i8 + k0) & 7;
            }
            sB[r * 57 + j] = make_float2(sr, si);
        }
        __syncthreads();
        if (t < 224) {     // stage 2
            int r = t / 56, k = t - r * 56;
            int kw = kw0 + r;
            if (kw <= 28) {
                float sr = 0.f, si = 0.f; int idx = 0;
                for (int n1 = 0; n1 < 7; ++n1) {
                    float2 a = sB[r * 57 + (n1 << 3) + (k & 7)];
                    float2 w = w56[idx];
                    sr = fmaf(a.x, w.x, fmaf(-a.y, w.y, sr));
                    si = fmaf(a.x, w.y, fmaf( a.y, w.x, si));
                    idx += k; if (idx >= 56) idx -= 56;
                }
                specS[bg * HP_ + kw * 56 + k] = make_float2(sr, si);
                float amp = sqrtf(sr * sr + si * si);
                float wgt = (kw == 0 || kw == 28) ? 1.f : 2.f;
                atomicAdd(&misc[lab_of(k * 56 + kw)], amp * wgt);
            }
        }
        __syncthreads();
        if (t < NB_) atomicAdd(&sums[bg * NB_ + t], misc[t]);
        __syncthreads();
    }
    grid.sync();

    // ---- Phase C: flip twiddles to inverse; FC + I1 ----
    if (t < 56) { float a = TWO_PI * (float)t / 56.f; w56[t] = make_float2(cosf(a), sinf(a)); }
    if (t < 8)  { float a = TWO_PI * (float)t / 8.f;  w8[t]  = make_float2(cosf(a), sinf(a)); }
    __syncthreads();
    for (int u = blk; u < UB_; u += gdim) {
        int bg = u >> 3, kw0 = (u & 7) * 4;
        int g = bg & 3;
        if (t < NB_) misc[t] = sums[bg * NB_ + t] * CNT.inv[t];   // pooled
        __syncthreads();
        if (t < NB_) {                                            // FC + leaky relu
            float acc = fc_b[g * NB_ + t];
            const float* wrow = &fc_w[(g * NB_ + t) * NB_];
            for (int n = 0; n < NB_; ++n) acc = fmaf(misc[n], wrow[n], acc);
            misc[64 + t] = acc >= 0.f ? acc : 0.01f * acc;        // att
        }
        __syncthreads();
        if (t < 224) {     // load + scale 4 kw rows
            int r = t / 56, kh = t - r * 56;
            int kw = kw0 + r;
            if (kw <= 28) {
                float2 v = specS[bg * HP_ + kw * 56 + kh];
                float a = misc[64 + lab_of(kh * 56 + kw)];
                sA[r * 57 + kh] = make_float2(v.x * a, v.y * a);
            }
        }
        __syncthreads();
        if (t < 224) {     // stage 1
            int r = t / 56, j = t - r * 56;
            int n1 = j >> 3, k0 = j & 7;
            float sr = 0.f, si = 0.f; int i8 = 0;
            for (int n2 = 0; n2 < 8; ++n2) {
                float2 a = sA[r * 57 + 7 * n2 + n1];
                float2 w = w8[i8];
                sr = fmaf(a.x, w.x, fmaf(-a.y, w.y, sr));
                si = fmaf(a.x, w.y, fmaf( a.y, w.x, si));
                i8 = (i8 + k0) & 7;
            }
            sB[r * 57 + j] = make_float2(sr, si);
        }
        __syncthreads();
        if (t < 224) {     // stage 2: output over h -> A_s layout (aliases tmpF)
            int r = t / 56, h = t - r * 56;
            int kw = kw0 + r;
            if (kw <= 28) {
                float sr = 0.f, si = 0.f; int idx = 0;
                for (int n1 = 0; n1 < 7; ++n1) {
                    float2 a = sB[r * 57 + (n1 << 3) + (h & 7)];
                    float2 w = w56[idx];
                    sr = fmaf(a.x, w.x, fmaf(-a.y, w.y, sr));
                    si = fmaf(a.x, w.y, fmaf( a.y, w.x, si));
                    idx += h; if (idx >= 56) idx -= 56;
                }
                tmpF[bg * HP_ + h * 29 + kw] = make_float2(sr, si);
            }
        }
        __syncthreads();
    }
    grid.sync();

    // ---- Phase D: I2 (real part) + plane min/max ----
    for (int u = blk; u < UA_; u += gdim) {
        int bg = u / 14, h0 = (u - bg * 14) * 4;
        if (t < 116) {     // load 29 + conjugate mirror to 56
            int r = t / 29, kw = t - r * 29;
            float2 v = tmpF[bg * HP_ + (h0 + r) * 29 + kw];
            sA[r * 57 + kw] = v;
            if (kw >= 1 && kw <= 27) sA[r * 57 + 56 - kw] = make_float2(v.x, -v.y);
        }
        __syncthreads();
        if (t < 224) {     // stage 1
            int r = t / 56, j = t - r * 56;
            int n1 = j >> 3, k0 = j & 7;
            float sr = 0.f, si = 0.f; int i8 = 0;
            for (int n2 = 0; n2 < 8; ++n2) {
                float2 a = sA[r * 57 + 7 * n2 + n1];
                float2 w = w8[i8];
                sr = fmaf(a.x, w.x, fmaf(-a.y, w.y, sr));
                si = fmaf(a.x, w.y, fmaf( a.y, w.x, si));
                i8 = (i8 + k0) & 7;
            }
            sB[r * 57 + j] = make_float2(sr, si);
        }
        __syncthreads();
        float lmn = INFINITY, lmx = -INFINITY;
        if (t < 224) {     // stage 2, real part only
            int r = t / 56, w = t - r * 56;
            float sr = 0.f; int idx = 0;
            for (int n1 = 0; n1 < 7; ++n1) {
                float2 a = sB[r * 57 + (n1 << 3) + (w & 7)];
                float2 tw = w56[idx];
                sr = fmaf(a.x, tw.x, fmaf(-a.y, tw.y, sr));
                idx += w; if (idx >= 56) idx -= 56;
            }
            float v = sr * (1.0f / (float)P_);
            nf[bg * P_ + (h0 + r) * 56 + w] = v;
            lmn = v; lmx = v;
        }
        misc[t] = lmn; misc[256 + t] = lmx;
        __syncthreads();
        for (int off = 128; off > 0; off >>= 1) {
            if (t < off) {
                misc[t]       = fminf(misc[t], misc[t + off]);
                misc[256 + t] = fmaxf(misc[256 + t], misc[256 + t + off]);
            }
            __syncthreads();
        }
        if (t == 0) {
            atomicMin(&mnmx[bg * 2 + 0], fkey(misc[0]));
            atomicMax(&mnmx[bg * 2 + 1], fkey(misc[256]));
        }
        __syncthreads();
    }
    grid.sync();

    // ---- Phase E: out = feature * (1 + gamma*attn) ----
    for (int i = blk * 256 + t; i < N4_; i += gdim * 256) {
        int b = i / (C_ * 784);
        int rem = i - b * (C_ * 784);
        int c = rem / 784;
        int p4 = rem - c * 784;
        int bg = (b << 2) | (c >> 6);
        float mn = fdec(mnmx[bg * 2 + 0]);
        float mx = fdec(mnmx[bg * 2 + 1]);
        float inv = 1.0f / (mx - mn);
        float4 f = ((const float4*)feature)[i];
        float4 v = ((const float4*)nf)[bg * 784 + p4];
        float gam = gamma[c];
        f4_t o;
        o.x = f.x + gam * f.x * ((v.x - mn) * inv);
        o.y = f.y + gam * f.y * ((v.y - mn) * inv);
        o.z = f.z + gam * f.z * ((v.z - mn) * inv);
        o.w = f.w + gam * f.w * ((v.w - mn) * inv);
        __builtin_nontemporal_store(o, ((f4_t*)out) + i);
    }
}

// ============ Fallback path: proven R13 five-kernel pipeline ============
__global__ __launch_bounds__(256) void comp_f1_kernel(const float* __restrict__ feature,
                                                      float2* __restrict__ tmpF,
                                                      float* __restrict__ sums,
                                                      unsigned* __restrict__ mnmx) {
    int blk = blockIdx.x, bg = blk / 14, rblk = blk - bg * 14, r0 = rblk * 4;
    int b = bg >> 2, g = bg & 3;
    int t = threadIdx.x;
    __shared__ float  sx[4][57];
    __shared__ float2 sT[4][57];
    __shared__ float2 w56[56];
    __shared__ float2 w8[8];
    if (rblk == 0) {
        if (t < NB_) sums[bg * NB_ + t] = 0.f;
        else if (t == NB_)     mnmx[bg * 2]     = 0xFFFFFFFFu;
        else if (t == NB_ + 1) mnmx[bg * 2 + 1] = 0u;
    }
    if (t < 56) { float a = -TWO_PI * (float)t / 56.f; w56[t] = make_float2(cosf(a), sinf(a)); }
    if (t < 8)  { float a = -TWO_PI * (float)t / 8.f;  w8[t]  = make_float2(cosf(a), sinf(a)); }
    if (t < 224) {
        const float* base = feature + (b * C_ + g * K_) * P_ + r0 * 56 + t;
        float sum = 0.f, mx = -INFINITY;
#pragma unroll 8
        for (int k = 0; k < K_; ++k) {
            float v = base[k * P_];
            sum += v;
            mx = fmaxf(mx, v);
        }
        sx[t / 56][t % 56] = sum * (1.f / 64.f) + mx;
    }
    __syncthreads();
    if (t < 224) {
        int r = t / 56, j = t - r * 56;
        int n1 = j >> 3, k0 = j & 7;
        float sr = 0.f, si = 0.f; int i8 = 0;
        for (int n2 = 0; n2 < 8; ++n2) {
            float v = sx[r][7 * n2 + n1];
            float2 w = w8[i8];
            sr = fmaf(v, w.x, sr);
            si = fmaf(v, w.y, si);
            i8 = (i8 + k0) & 7;
        }
        sT[r][j] = make_float2(sr, si);
    }
    __syncthreads();
    if (t < 116) {
        int r = t & 3, k = t >> 2;
        float sr = 0.f, si = 0.f; int idx = 0;
        for (int n1 = 0; n1 < 7; ++n1) {
            float2 a = sT[r][(n1 << 3) + (k & 7)];
            float2 w = w56[idx];
            sr = fmaf(a.x, w.x, fmaf(-a.y, w.y, sr));
            si = fmaf(a.x, w.y, fmaf( a.y, w.x, si));
            idx += k; if (idx >= 56) idx -= 56;
        }
        tmpF[bg * HP_ + k * 56 + (r0 + r)] = make_float2(sr, si);
    }
}

__global__ __launch_bounds__(256) void f2_kernel(const float2* __restrict__ tmpF,
                                                 float2* __restrict__ specS,
                                                 float* __restrict__ sums) {
    int blk = blockIdx.x, bg = blk >> 3, kw0 = (blk & 7) * 4;
    __shared__ float2 sx[4][57];
    __shared__ float2 sT[4][57];
    __shared__ float2 w56[56];
    __shared__ float2 w8[8];
    __shared__ float  sbins[NB_];
    int t = threadIdx.x;
    if (t < 56) { float a = -TWO_PI * (float)t / 56.f; w56[t] = make_float2(cosf(a), sinf(a)); }
    if (t < 8)  { float a = -TWO_PI * (float)t / 8.f;  w8[t]  = make_float2(cosf(a), sinf(a)); }
    if (t < NB_) sbins[t] = 0.f;
    if (t < 224) {
        int r = t / 56, c = t - r * 56;
        if (kw0 + r <= 28) sx[r][c] = tmpF[bg * HP_ + (kw0 + r) * 56 + c];
    }
    __syncthreads();
    if (t < 224) {
        int r = t / 56, j = t - r * 56;
        int n1 = j >> 3, k0 = j & 7;
        float sr = 0.f, si = 0.f; int i8 = 0;
        for (int n2 = 0; n2 < 8; ++n2) {
            float2 a = sx[r][7 * n2 + n1];
            float2 w = w8[i8];
            sr = fmaf(a.x, w.x, fmaf(-a.y, w.y, sr));
            si = fmaf(a.x, w.y, fmaf( a.y, w.x, si));
            i8 = (i8 + k0) & 7;
        }
        sT[r][j] = make_float2(sr, si);
    }
    __syncthreads();
    if (t < 224) {
        int r = t / 56, k = t - r * 56;
        int kw = kw0 + r;
        if (kw <= 28) {
            float sr = 0.f, si = 0.f; int idx = 0;
            for (int n1 = 0; n1 < 7; ++n1) {
                float2 a = sT[r][(n1 << 3) + (k & 7)];
                float2 w = w56[idx];
                sr = fmaf(a.x, w.x, fmaf(-a.y, w.y, sr));
                si = fmaf(a.x, w.y, fmaf( a.y, w.x, si));
                idx += k; if (idx >= 56) idx -= 56;
            }
            specS[bg * HP_ + kw * 56 + k] = make_float2(sr, si);
            float amp = sqrtf(sr * sr + si * si);
            float wgt = (kw == 0 || kw == 28) ? 1.f : 2.f;
            atomicAdd(&sbins[lab_of(k * 56 + kw)], amp * wgt);
        }
    }
    __syncthreads();
    if (t < NB_) atomicAdd(&sums[bg * NB_ + t], sbins[t]);
}

__global__ __launch_bounds__(256) void i1fc_kernel(const float2* __restrict__ specS,
                                                   const float* __restrict__ sums,
                                                   const float* __restrict__ fc_w,
                                                   const float* __restrict__ fc_b,
                                                   float2* __restrict__ A_s) {
    int blk = blockIdx.x, bg = blk >> 3, kw0 = (blk & 7) * 4;
    int g = bg & 3;
    __shared__ float2 sx[4][57];
    __shared__ float2 sT[4][57];
    __shared__ float2 w56[56];
    __shared__ float2 w8[8];
    __shared__ float  s_pool[NB_], s_att[NB_];
    int t = threadIdx.x;
    if (t < 56) { float a = TWO_PI * (float)t / 56.f; w56[t] = make_float2(cosf(a), sinf(a)); }
    if (t < 8)  { float a = TWO_PI * (float)t / 8.f;  w8[t]  = make_float2(cosf(a), sinf(a)); }
    if (t < NB_) s_pool[t] = sums[bg * NB_ + t] * CNT.inv[t];
    __syncthreads();
    if (t < NB_) {
        float acc = fc_b[g * NB_ + t];
        const float* wrow = &fc_w[(g * NB_ + t) * NB_];
        for (int n = 0; n < NB_; ++n) acc = fmaf(s_pool[n], wrow[n], acc);
        s_att[t] = acc >= 0.f ? acc : 0.01f * acc;
    }
    __syncthreads();
    if (t < 224) {
        int r = t / 56, kh = t - r * 56;
        int kw = kw0 + r;
        if (kw <= 28) {
            float2 v = specS[bg * HP_ + kw * 56 + kh];
            float a = s_att[lab_of(kh * 56 + kw)];
            sx[r][kh] = make_float2(v.x * a, v.y * a);
        }
    }
    __syncthreads();
    if (t < 224) {
        int r = t / 56, j = t - r * 56;
        int n1 = j >> 3, k0 = j & 7;
        float sr = 0.f, si = 0.f; int i8 = 0;
        for (int n2 = 0; n2 < 8; ++n2) {
            float2 a = sx[r][7 * n2 + n1];
            float2 w = w8[i8];
            sr = fmaf(a.x, w.x, fmaf(-a.y, w.y, sr));
            si = fmaf(a.x, w.y, fmaf( a.y, w.x, si));
            i8 = (i8 + k0) & 7;
        }
        sT[r][j] = make_float2(sr, si);
    }
    __syncthreads();
    if (t < 224) {
        int r = t / 56, h = t - r * 56;
        int kw = kw0 + r;
        if (kw <= 28) {
            float sr = 0.f, si = 0.f; int idx = 0;
            for (int n1 = 0; n1 < 7; ++n1) {
                float2 a = sT[r][(n1 << 3) + (h & 7)];
                float2 w = w56[idx];
                sr = fmaf(a.x, w.x, fmaf(-a.y, w.y, sr));
                si = fmaf(a.x, w.y, fmaf( a.y, w.x, si));
                idx += h; if (idx >= 56) idx -= 56;
            }
            A_s[bg * HP_ + h * 29 + kw] = make_float2(sr, si);
        }
    }
}

__global__ __launch_bounds__(256) void i2_kernel(const float2* __restrict__ A_s,
                                                 float* __restrict__ nf,
                                                 unsigned* __restrict__ mnmx) {
    int blk = blockIdx.x, bg = blk / 14, h0 = (blk - bg * 14) * 4;
    __shared__ float2 sx[4][57];
    __shared__ float2 sT[4][57];
    __shared__ float2 w56[56];
    __shared__ float2 w8[8];
    __shared__ float  red_mn[256], red_mx[256];
    int t = threadIdx.x;
    if (t < 56) { float a = TWO_PI * (float)t / 56.f; w56[t] = make_float2(cosf(a), sinf(a)); }
    if (t < 8)  { float a = TWO_PI * (float)t / 8.f;  w8[t]  = make_float2(cosf(a), sinf(a)); }
    if (t < 116) {
        int r = t / 29, kw = t - r * 29;
        float2 v = A_s[bg * HP_ + (h0 + r) * 29 + kw];
        sx[r][kw] = v;
        if (kw >= 1 && kw <= 27) sx[r][56 - kw] = make_float2(v.x, -v.y);
    }
    __syncthreads();
    if (t < 224) {
        int r = t / 56, j = t - r * 56;
        int n1 = j >> 3, k0 = j & 7;
        float sr = 0.f, si = 0.f; int i8 = 0;
        for (int n2 = 0; n2 < 8; ++n2) {
            float2 a = sx[r][7 * n2 + n1];
            float2 w = w8[i8];
            sr = fmaf(a.x, w.x, fmaf(-a.y, w.y, sr));
            si = fmaf(a.x, w.y, fmaf( a.y, w.x, si));
            i8 = (i8 + k0) & 7;
        }
        sT[r][j] = make_float2(sr, si);
    }
    __syncthreads();
    float lmn = INFINITY, lmx = -INFINITY;
    if (t < 224) {
        int r = t / 56, w = t - r * 56;
        float sr = 0.f; int idx = 0;
        for (int n1 = 0; n1 < 7; ++n1) {
            float2 a = sT[r][(n1 << 3) + (w & 7)];
            float2 tw = w56[idx];
            sr = fmaf(a.x, tw.x, fmaf(-a.y, tw.y, sr));
            idx += w; if (idx >= 56) idx -= 56;
        }
        float v = sr * (1.0f / (float)P_);
        nf[bg * P_ + (h0 + r) * 56 + w] = v;
        lmn = v; lmx = v;
    }
    red_mn[t] = lmn; red_mx[t] = lmx;
    __syncthreads();
    for (int off = 128; off > 0; off >>= 1) {
        if (t < off) {
            red_mn[t] = fminf(red_mn[t], red_mn[t + off]);
            red_mx[t] = fmaxf(red_mx[t], red_mx[t + off]);
        }
        __syncthreads();
    }
    if (t == 0) {
        atomicMin(&mnmx[bg * 2 + 0], fkey(red_mn[0]));
        atomicMax(&mnmx[bg * 2 + 1], fkey(red_mx[0]));
    }
}

__global__ __launch_bounds__(256) void final_kernel(const float* __restrict__ feature,
                                                    const float* __restrict__ gamma,
                                                    const float* __restrict__ nf,
                                                    const unsigned* __restrict__ mnmx,
                                                    float* __restrict__ out) {
    int i = blockIdx.x * 256 + threadIdx.x;
    int b = i / (C_ * 784);
    int rem = i - b * (C_ * 784);
    int c = rem / 784;
    int p4 = rem - c * 784;
    int bg = (b << 2) | (c >> 6);
    float mn = fdec(mnmx[bg * 2 + 0]);
    float mx = fdec(mnmx[bg * 2 + 1]);
    float inv = 1.0f / (mx - mn);
    float4 f = ((const float4*)feature)[i];
    float4 v = ((const float4*)nf)[bg * 784 + p4];
    float gam = gamma[c];
    f4_t o;
    o.x = f.x + gam * f.x * ((v.x - mn) * inv);
    o.y = f.y + gam * f.y * ((v.y - mn) * inv);
    o.z = f.z + gam * f.z * ((v.z - mn) * inv);
    o.w = f.w + gam * f.w * ((v.w - mn) * inv);
    __builtin_nontemporal_store(o, ((f4_t*)out) + i);
}

extern "C" void kernel_launch(void* const* d_in, const int* in_sizes, int n_in,
                              void* d_out, int out_size, void* d_ws, size_t ws_size,
                              hipStream_t stream) {
    const float* feature = (const float*)d_in[0];
    const float* gamma   = (const float*)d_in[1];
    const float* fc_w    = (const float*)d_in[2];
    const float* fc_b    = (const float*)d_in[3];

    float* ws = (float*)d_ws;
    float2*   tmpF  = (float2*)ws;                // HP_*BG_ = 207872 float2 (reused as A_s)
    float2*   specS = (float2*)(ws + 415744);     // 207872 float2
    float*    nf    = ws + 831488;                // 401408
    float*    sums  = ws + 1232896;               // 3712
    unsigned* mnmx  = (unsigned*)(ws + 1236608);  // 256
    float*    out   = (float*)d_out;

    // Host-side (capture-safe) queries to size the cooperative grid.
    int dev = 0;
    hipGetDevice(&dev);
    int coop = 0, ncu = 0, occ = 0;
    hipDeviceGetAttribute(&coop, hipDeviceAttributeCooperativeLaunch, dev);
    hipDeviceGetAttribute(&ncu, hipDeviceAttributeMultiprocessorCount, dev);
    hipOccupancyMaxActiveBlocksPerMultiprocessor(&occ, fused_kernel, 256, 0);
    long grid = (long)occ * (long)ncu;
    if (grid > UA_) grid = UA_;

    if (coop && grid > 0) {
        void* args[] = { (void*)&feature, (void*)&gamma, (void*)&fc_w, (void*)&fc_b,
                         (void*)&tmpF, (void*)&specS, (void*)&nf, (void*)&sums,
                         (void*)&mnmx, (void*)&out };
        hipError_t e = hipLaunchCooperativeKernel(fused_kernel, dim3((unsigned)grid),
                                                  dim3(256), args, 0, stream);
        if (e == hipSuccess) return;
    }

    // Fallback: proven 5-kernel path (R13, 72.8 us).
    comp_f1_kernel<<<BG_ * 14, 256, 0, stream>>>(feature, tmpF, sums, mnmx);
    f2_kernel     <<<BG_ * 8, 256, 0, stream>>>(tmpF, specS, sums);
    i1fc_kernel   <<<BG_ * 8, 256, 0, stream>>>(specS, sums, fc_w, fc_b, tmpF);
    i2_kernel     <<<BG_ * 14, 256, 0, stream>>>(tmpF, nf, mnmx);
    final_kernel  <<<N4_ / 256, 256, 0, stream>>>(feature, gamma, nf, mnmx, out);
}

// Round 16
// 72.625 us; speedup vs baseline: 4.1396x; 4.1396x over previous
//
#include <hip/hip_runtime.h>
#include <math.h>

// Problem constants: B=32, C=256, H=W=56, group=4, d=1
constexpr int B_  = 32;
constexpr int C_  = 256;
constexpr int G_  = 4;
constexpr int K_  = 64;
constexpr int P_  = 3136;        // 56*56
constexpr int NB_ = 29;
constexpr int BG_ = 128;         // B*G
constexpr int CP_ = C_ * P_;
constexpr int N_  = B_ * CP_;
constexpr int N4_ = N_ / 4;
constexpr int HP_ = 29 * 56;     // 1624, half-plane points
constexpr float TWO_PI = 6.283185307179586f;

typedef float f4_t __attribute__((ext_vector_type(4)));   // native vec for nt-store

// Radial bin label in RAW (unshifted) coords, p = a*56 + b (symmetric in a,b
// and under a->56-a, b->56-b). Exact integer isqrt -> constexpr-safe.
__host__ __device__ constexpr int lab_of(int p) {
    int h = p / 56, w = p - h * 56;
    int hh = ((h + 28) % 56) - 28;
    int ww = ((w + 28) % 56) - 28;
    int r2 = hh * hh + ww * ww;
    int rf = 0;
    while ((rf + 1) * (rf + 1) <= r2) ++rf;
    if (rf > 28) rf = 28;
    return rf;
}

// Compile-time radial bin inverse counts (pure geometry).
struct CntTable { float inv[NB_]; };
constexpr CntTable make_cnt() {
    CntTable t{};
    int c[NB_] = {};
    for (int p = 0; p < P_; ++p) ++c[lab_of(p)];
    for (int i = 0; i < NB_; ++i) t.inv[i] = 1.0f / (float)c[i];
    return t;
}
constexpr CntTable CNT = make_cnt();

// Ordered-uint key for float atomic min/max.
__device__ __forceinline__ unsigned fkey(float f) {
    unsigned u = __float_as_uint(f);
    return (u & 0x80000000u) ? ~u : (u | 0x80000000u);
}
__device__ __forceinline__ float fdec(unsigned k) {
    return (k & 0x80000000u) ? __uint_as_float(k ^ 0x80000000u) : __uint_as_float(~k);
}

// ---------------------------------------------------------------------------
// Radix 7x8 over a 56-line: n = 7*n2 + n1,
//   X[k] = sum_{n1<7} e^{s 2pi i n1 k/56} * T[n1][k&7],
//   T[n1][k0] = sum_{n2<8} x[7*n2+n1] e^{s 2pi i n2 k0/8}
// ---------------------------------------------------------------------------

// Kernel 1: fused comp + row-DFT (F1, radix 7x8, real input), Hermitian half
// only (kw<=28). One block per (bg, 4 h-rows); per-lane scalar feature loads
// are wave-coalesced. rblk==0 re-inits sums/mnmx.
__global__ __launch_bounds__(256) void comp_f1_kernel(const float* __restrict__ feature,
                                                      float2* __restrict__ tmpF,
                                                      float* __restrict__ sums,
                                                      unsigned* __restrict__ mnmx) {
    int blk = blockIdx.x, bg = blk / 14, rblk = blk - bg * 14, r0 = rblk * 4;
    int b = bg >> 2, g = bg & 3;
    int t = threadIdx.x;
    __shared__ float  sx[4][57];
    __shared__ float2 sT[4][57];
    __shared__ float2 w56[56];
    __shared__ float2 w8[8];
    if (rblk == 0) {
        if (t < NB_) sums[bg * NB_ + t] = 0.f;
        else if (t == NB_)     mnmx[bg * 2]     = 0xFFFFFFFFu;
        else if (t == NB_ + 1) mnmx[bg * 2 + 1] = 0u;
    }
    if (t < 56) { float a = -TWO_PI * (float)t / 56.f; w56[t] = make_float2(cosf(a), sinf(a)); }
    if (t < 8)  { float a = -TWO_PI * (float)t / 8.f;  w8[t]  = make_float2(cosf(a), sinf(a)); }
    if (t < 224) {
        const float* base = feature + (b * C_ + g * K_) * P_ + r0 * 56 + t;
        float sum = 0.f, mx = -INFINITY;
#pragma unroll 8
        for (int k = 0; k < K_; ++k) {
            float v = base[k * P_];
            sum += v;
            mx = fmaxf(mx, v);
        }
        sx[t / 56][t % 56] = sum * (1.f / 64.f) + mx;
    }
    __syncthreads();
    if (t < 224) {     // stage 1 (real input): T[r][n1*8+k0]
        int r = t / 56, j = t - r * 56;
        int n1 = j >> 3, k0 = j & 7;
        float sr = 0.f, si = 0.f; int i8 = 0;
        for (int n2 = 0; n2 < 8; ++n2) {
            float v = sx[r][7 * n2 + n1];
            float2 w = w8[i8];
            sr = fmaf(v, w.x, sr);
            si = fmaf(v, w.y, si);
            i8 = (i8 + k0) & 7;
        }
        sT[r][j] = make_float2(sr, si);
    }
    __syncthreads();
    if (t < 116) {     // stage 2: 29 kw x 4 rows
        int r = t & 3, k = t >> 2;    // k = kw 0..28
        float sr = 0.f, si = 0.f; int idx = 0;
        for (int n1 = 0; n1 < 7; ++n1) {
            float2 a = sT[r][(n1 << 3) + (k & 7)];
            float2 w = w56[idx];
            sr = fmaf(a.x, w.x, fmaf(-a.y, w.y, sr));
            si = fmaf(a.x, w.y, fmaf( a.y, w.x, si));
            idx += k; if (idx >= 56) idx -= 56;
        }
        tmpF[bg * HP_ + k * 56 + (r0 + r)] = make_float2(sr, si);
    }
}

// Kernel 2: F2 (col DFT over h, radix 7x8) on the kw half + radial bin sums
// (weight 2 for kw=1..27 mirrors). 8 blocks/plane x 4 kw-lines.
__global__ __launch_bounds__(256) void f2_kernel(const float2* __restrict__ tmpF,
                                                 float2* __restrict__ specS,
                                                 float* __restrict__ sums) {
    int blk = blockIdx.x, bg = blk >> 3, kw0 = (blk & 7) * 4;
    __shared__ float2 sx[4][57];
    __shared__ float2 sT[4][57];
    __shared__ float2 w56[56];
    __shared__ float2 w8[8];
    __shared__ float  sbins[NB_];
    int t = threadIdx.x;
    if (t < 56) { float a = -TWO_PI * (float)t / 56.f; w56[t] = make_float2(cosf(a), sinf(a)); }
    if (t < 8)  { float a = -TWO_PI * (float)t / 8.f;  w8[t]  = make_float2(cosf(a), sinf(a)); }
    if (t < NB_) sbins[t] = 0.f;
    if (t < 224) {
        int r = t / 56, c = t - r * 56;
        if (kw0 + r <= 28) sx[r][c] = tmpF[bg * HP_ + (kw0 + r) * 56 + c];
    }
    __syncthreads();
    if (t < 224) {     // stage 1
        int r = t / 56, j = t - r * 56;
        int n1 = j >> 3, k0 = j & 7;
        float sr = 0.f, si = 0.f; int i8 = 0;
        for (int n2 = 0; n2 < 8; ++n2) {
            float2 a = sx[r][7 * n2 + n1];
            float2 w = w8[i8];
            sr = fmaf(a.x, w.x, fmaf(-a.y, w.y, sr));
            si = fmaf(a.x, w.y, fmaf( a.y, w.x, si));
            i8 = (i8 + k0) & 7;
        }
        sT[r][j] = make_float2(sr, si);
    }
    __syncthreads();
    if (t < 224) {     // stage 2
        int r = t / 56, k = t - r * 56;
        int kw = kw0 + r;
        if (kw <= 28) {
            float sr = 0.f, si = 0.f; int idx = 0;
            for (int n1 = 0; n1 < 7; ++n1) {
                float2 a = sT[r][(n1 << 3) + (k & 7)];
                float2 w = w56[idx];
                sr = fmaf(a.x, w.x, fmaf(-a.y, w.y, sr));
                si = fmaf(a.x, w.y, fmaf( a.y, w.x, si));
                idx += k; if (idx >= 56) idx -= 56;
            }
            specS[bg * HP_ + kw * 56 + k] = make_float2(sr, si);
            float amp = sqrtf(sr * sr + si * si);
            float wgt = (kw == 0 || kw == 28) ? 1.f : 2.f;
            atomicAdd(&sbins[lab_of(k * 56 + kw)], amp * wgt);
        }
    }
    __syncthreads();
    if (t < NB_) atomicAdd(&sums[bg * NB_ + t], sbins[t]);
}

// Kernel 3: redundant per-block FC + I1 (inverse DFT over kh, radix 7x8) on
// the kw half. 8 blocks/plane x 4 kw-rows. A_s[bg][h][kw], kw=0..28.
__global__ __launch_bounds__(256) void i1fc_kernel(const float2* __restrict__ specS,
                                                   const float* __restrict__ sums,
                                                   const float* __restrict__ fc_w,
                                                   const float* __restrict__ fc_b,
                                                   float2* __restrict__ A_s) {
    int blk = blockIdx.x, bg = blk >> 3, kw0 = (blk & 7) * 4;
    int g = bg & 3;
    __shared__ float2 sx[4][57];
    __shared__ float2 sT[4][57];
    __shared__ float2 w56[56];
    __shared__ float2 w8[8];
    __shared__ float  s_pool[NB_], s_att[NB_];
    int t = threadIdx.x;
    if (t < 56) { float a = TWO_PI * (float)t / 56.f; w56[t] = make_float2(cosf(a), sinf(a)); }
    if (t < 8)  { float a = TWO_PI * (float)t / 8.f;  w8[t]  = make_float2(cosf(a), sinf(a)); }
    if (t < NB_) s_pool[t] = sums[bg * NB_ + t] * CNT.inv[t];
    __syncthreads();
    if (t < NB_) {
        float acc = fc_b[g * NB_ + t];
        const float* wrow = &fc_w[(g * NB_ + t) * NB_];
        for (int n = 0; n < NB_; ++n) acc = fmaf(s_pool[n], wrow[n], acc);
        s_att[t] = acc >= 0.f ? acc : 0.01f * acc;
    }
    __syncthreads();
    if (t < 224) {     // load + scale 4 kw rows
        int r = t / 56, kh = t - r * 56;
        int kw = kw0 + r;
        if (kw <= 28) {
            float2 v = specS[bg * HP_ + kw * 56 + kh];
            float a = s_att[lab_of(kh * 56 + kw)];
            sx[r][kh] = make_float2(v.x * a, v.y * a);
        }
    }
    __syncthreads();
    if (t < 224) {     // stage 1
        int r = t / 56, j = t - r * 56;
        int n1 = j >> 3, k0 = j & 7;
        float sr = 0.f, si = 0.f; int i8 = 0;
        for (int n2 = 0; n2 < 8; ++n2) {
            float2 a = sx[r][7 * n2 + n1];
            float2 w = w8[i8];
            sr = fmaf(a.x, w.x, fmaf(-a.y, w.y, sr));
            si = fmaf(a.x, w.y, fmaf( a.y, w.x, si));
            i8 = (i8 + k0) & 7;
        }
        sT[r][j] = make_float2(sr, si);
    }
    __syncthreads();
    if (t < 224) {     // stage 2: output over h
        int r = t / 56, h = t - r * 56;
        int kw = kw0 + r;
        if (kw <= 28) {
            float sr = 0.f, si = 0.f; int idx = 0;
            for (int n1 = 0; n1 < 7; ++n1) {
                float2 a = sT[r][(n1 << 3) + (h & 7)];
                float2 w = w56[idx];
                sr = fmaf(a.x, w.x, fmaf(-a.y, w.y, sr));
                si = fmaf(a.x, w.y, fmaf( a.y, w.x, si));
                idx += h; if (idx >= 56) idx -= 56;
            }
            A_s[bg * HP_ + h * 29 + kw] = make_float2(sr, si);
        }
    }
}

// Kernel 4: I2 (inverse DFT over kw, radix 7x8, real part) + plane min/max.
// Block owns 4 h rows; loads the kw half, mirrors by conjugation in LDS.
__global__ __launch_bounds__(256) void i2_kernel(const float2* __restrict__ A_s,
                                                 float* __restrict__ nf,
                                                 unsigned* __restrict__ mnmx) {
    int blk = blockIdx.x, bg = blk / 14, h0 = (blk - bg * 14) * 4;
    __shared__ float2 sx[4][57];
    __shared__ float2 sT[4][57];
    __shared__ float2 w56[56];
    __shared__ float2 w8[8];
    __shared__ float  red_mn[256], red_mx[256];
    int t = threadIdx.x;
    if (t < 56) { float a = TWO_PI * (float)t / 56.f; w56[t] = make_float2(cosf(a), sinf(a)); }
    if (t < 8)  { float a = TWO_PI * (float)t / 8.f;  w8[t]  = make_float2(cosf(a), sinf(a)); }
    if (t < 116) {     // load 29 + mirror to 56 (conjugate)
        int r = t / 29, kw = t - r * 29;
        float2 v = A_s[bg * HP_ + (h0 + r) * 29 + kw];
        sx[r][kw] = v;
        if (kw >= 1 && kw <= 27) sx[r][56 - kw] = make_float2(v.x, -v.y);
    }
    __syncthreads();
    if (t < 224) {     // stage 1
        int r = t / 56, j = t - r * 56;
        int n1 = j >> 3, k0 = j & 7;
        float sr = 0.f, si = 0.f; int i8 = 0;
        for (int n2 = 0; n2 < 8; ++n2) {
            float2 a = sx[r][7 * n2 + n1];
            float2 w = w8[i8];
            sr = fmaf(a.x, w.x, fmaf(-a.y, w.y, sr));
            si = fmaf(a.x, w.y, fmaf( a.y, w.x, si));
            i8 = (i8 + k0) & 7;
        }
        sT[r][j] = make_float2(sr, si);
    }
    __syncthreads();
    float lmn = INFINITY, lmx = -INFINITY;
    if (t < 224) {     // stage 2, real part only
        int r = t / 56, w = t - r * 56;
        float sr = 0.f; int idx = 0;
        for (int n1 = 0; n1 < 7; ++n1) {
            float2 a = sT[r][(n1 << 3) + (w & 7)];
            float2 tw = w56[idx];
            sr = fmaf(a.x, tw.x, fmaf(-a.y, tw.y, sr));
            idx += w; if (idx >= 56) idx -= 56;
        }
        float v = sr * (1.0f / (float)P_);
        nf[bg * P_ + (h0 + r) * 56 + w] = v;
        lmn = v; lmx = v;
    }
    red_mn[t] = lmn; red_mx[t] = lmx;
    __syncthreads();
    for (int off = 128; off > 0; off >>= 1) {
        if (t < off) {
            red_mn[t] = fminf(red_mn[t], red_mn[t + off]);
            red_mx[t] = fmaxf(red_mx[t], red_mx[t + off]);
        }
        __syncthreads();
    }
    if (t == 0) {
        atomicMin(&mnmx[bg * 2 + 0], fkey(red_mn[0]));
        atomicMax(&mnmx[bg * 2 + 1], fkey(red_mx[0]));
    }
}

// Kernel 5: out = feature + gamma[c] * feature * attn_map, float4, nt stores.
__global__ __launch_bounds__(256) void final_kernel(const float* __restrict__ feature,
                                                    const float* __restrict__ gamma,
                                                    const float* __restrict__ nf,
                                                    const unsigned* __restrict__ mnmx,
                                                    float* __restrict__ out) {
    int i = blockIdx.x * 256 + threadIdx.x;      // over N4_ (exact)
    int b = i / (C_ * 784);
    int rem = i - b * (C_ * 784);
    int c = rem / 784;
    int p4 = rem - c * 784;
    int bg = (b << 2) | (c >> 6);
    float mn = fdec(mnmx[bg * 2 + 0]);
    float mx = fdec(mnmx[bg * 2 + 1]);
    float inv = 1.0f / (mx - mn);
    float4 f = ((const float4*)feature)[i];
    float4 v = ((const float4*)nf)[bg * 784 + p4];
    float gam = gamma[c];
    f4_t o;
    o.x = f.x + gam * f.x * ((v.x - mn) * inv);
    o.y = f.y + gam * f.y * ((v.y - mn) * inv);
    o.z = f.z + gam * f.z * ((v.z - mn) * inv);
    o.w = f.w + gam * f.w * ((v.w - mn) * inv);
    __builtin_nontemporal_store(o, ((f4_t*)out) + i);
}

extern "C" void kernel_launch(void* const* d_in, const int* in_sizes, int n_in,
                              void* d_out, int out_size, void* d_ws, size_t ws_size,
                              hipStream_t stream) {
    const float* feature = (const float*)d_in[0];
    const float* gamma   = (const float*)d_in[1];
    const float* fc_w    = (const float*)d_in[2];
    const float* fc_b    = (const float*)d_in[3];

    float* ws = (float*)d_ws;
    float2*   tmpF    = (float2*)ws;                // HP_*BG_ = 207872 float2
    float2*   specS   = (float2*)(ws + 415744);     // 207872 float2
    float*    nf      = ws + 831488;                // 401408
    float*    sums    = ws + 1232896;               // 3712
    unsigned* mnmx    = (unsigned*)(ws + 1236608);  // 256
    float2*   A_s     = tmpF;                       // reuse (tmpF dead after f2)
    float*    out     = (float*)d_out;

    comp_f1_kernel<<<BG_ * 14, 256, 0, stream>>>(feature, tmpF, sums, mnmx);
    f2_kernel     <<<BG_ * 8, 256, 0, stream>>>(tmpF, specS, sums);
    i1fc_kernel   <<<BG_ * 8, 256, 0, stream>>>(specS, sums, fc_w, fc_b, A_s);
    i2_kernel     <<<BG_ * 14, 256, 0, stream>>>(A_s, nf, mnmx);
    final_kernel  <<<N4_ / 256, 256, 0, stream>>>(feature, gamma, nf, mnmx, out);
}